// Round 6
// baseline (24.377 us; speedup 1.0000x reference)
//
#include <hip/hip_runtime.h>

// out[k] = sum_n sum_{i,j} frac[n,i]*frac[n,j]*cg[i,j,k]
//        = sum_{i,j} M[i][j] * cg[i,j,k],  M = sum_n x x^T (3x3 symmetric, 6 uniques)
//
// Pass 1: each wave processes 2 chunks of 12 KB (768 float4 = 1024 rows each).
//   Lane owns 48 B = 3 consecutive float4 = 4 COMPLETE rows per segment
//   (no straddle, no shuffles), 4 segments x 3 loads = 12 dwordx4 straight-line.
//   GRID=1024 (4 blocks/CU, 16 waves/CU) guarantees ALL blocks co-resident in
//   one round for any VGPR <= 128 — R5 post-mortem: GRID=2048 likely ran a
//   ~33% straggler second round at low occupancy (VGPR ~80 -> 6 blocks/CU).
// Pass 2: 1 block, coalesced float4 reads of transposed partials + generic
//   row tail + cg contraction.
//
// R3 post-mortem: no cross-block coherence (agent-scope release per block
// = per-block L2 writeback = 131 us). Two stream-ordered kernels.

constexpr int BLK  = 256;
constexpr int GRID = 1024;
constexpr int WPB  = BLK / 64;              // 4 waves per block
constexpr long NWAVES = (long)GRID * WPB;   // 4096
// chunk = 768 float4 = 3072 floats = 1024 rows = 12 KB

#define ACC6(x, y, z)                                              \
    do {                                                           \
        s00 = fmaf((x), (x), s00); s01 = fmaf((x), (y), s01);      \
        s02 = fmaf((x), (z), s02); s11 = fmaf((y), (y), s11);      \
        s12 = fmaf((y), (z), s12); s22 = fmaf((z), (z), s22);      \
    } while (0)

__global__ __launch_bounds__(BLK) void tp_partial(const float* __restrict__ frac,
                                                  float* __restrict__ ws,
                                                  long nchunks) {
    const int  lane = threadIdx.x & 63;
    const int  w    = threadIdx.x >> 6;
    const long wglb = (long)blockIdx.x * WPB + w;
    const float4* __restrict__ f4 = reinterpret_cast<const float4*>(frac);

    float s00 = 0.f, s01 = 0.f, s02 = 0.f, s11 = 0.f, s12 = 0.f, s22 = 0.f;

    #pragma unroll 2
    for (long c = wglb; c < nchunks; c += NWAVES) {   // trip count 2 for N=2^23
        const long base = c * 768 + lane * 3;
        float4 v[12];
        #pragma unroll
        for (int s = 0; s < 4; ++s)
            #pragma unroll
            for (int k = 0; k < 3; ++k)
                v[s * 3 + k] = f4[base + 192 * s + k];   // 12 loads in flight

        #pragma unroll
        for (int s = 0; s < 4; ++s) {
            const float4 a = v[s * 3 + 0];
            const float4 b = v[s * 3 + 1];
            const float4 d = v[s * 3 + 2];
            ACC6(a.x, a.y, a.z);
            ACC6(a.w, b.x, b.y);
            ACC6(b.z, b.w, d.x);
            ACC6(d.y, d.z, d.w);
        }
    }

    // 64-lane butterfly reduction
    #pragma unroll
    for (int off = 32; off > 0; off >>= 1) {
        s00 += __shfl_down(s00, off);
        s01 += __shfl_down(s01, off);
        s02 += __shfl_down(s02, off);
        s11 += __shfl_down(s11, off);
        s12 += __shfl_down(s12, off);
        s22 += __shfl_down(s22, off);
    }

    __shared__ float red[WPB][6];
    if (lane == 0) {
        red[w][0] = s00; red[w][1] = s01; red[w][2] = s02;
        red[w][3] = s11; red[w][4] = s12; red[w][5] = s22;
    }
    __syncthreads();
    if (threadIdx.x < 6) {
        float v = red[0][threadIdx.x] + red[1][threadIdx.x]
                + red[2][threadIdx.x] + red[3][threadIdx.x];
        ws[threadIdx.x * GRID + blockIdx.x] = v;   // transposed [6][GRID]
    }
}

__global__ __launch_bounds__(BLK) void tp_final(const float* __restrict__ frac,
                                                const float* __restrict__ ws,
                                                const float* __restrict__ cg,
                                                float* __restrict__ out,
                                                long tail_row, long nrows) {
    const float4* __restrict__ w4 = reinterpret_cast<const float4*>(ws); // [6][GRID/4]
    constexpr int Q = GRID / 4;   // 256 float4 per component = BLK

    float s[6];
    #pragma unroll
    for (int c = 0; c < 6; ++c) {
        float4 a = w4[c * Q + threadIdx.x];
        s[c] = (a.x + a.y) + (a.z + a.w);
    }

    // generic row tail (none for N = 2^23)
    for (long r = tail_row + threadIdx.x; r < nrows; r += BLK) {
        float x = frac[3 * r + 0], y = frac[3 * r + 1], z = frac[3 * r + 2];
        s[0] = fmaf(x, x, s[0]); s[1] = fmaf(x, y, s[1]); s[2] = fmaf(x, z, s[2]);
        s[3] = fmaf(y, y, s[3]); s[4] = fmaf(y, z, s[4]); s[5] = fmaf(z, z, s[5]);
    }

    #pragma unroll
    for (int off = 32; off > 0; off >>= 1) {
        #pragma unroll
        for (int c = 0; c < 6; ++c) s[c] += __shfl_down(s[c], off);
    }

    __shared__ float red[BLK / 64][6];
    const int lane = threadIdx.x & 63;
    const int wave = threadIdx.x >> 6;
    if (lane == 0) {
        #pragma unroll
        for (int c = 0; c < 6; ++c) red[wave][c] = s[c];
    }
    __syncthreads();

    __shared__ float M[9];
    if (threadIdx.x == 0) {
        float t[6];
        #pragma unroll
        for (int c = 0; c < 6; ++c)
            t[c] = red[0][c] + red[1][c] + red[2][c] + red[3][c];
        M[0] = t[0];  M[1] = t[1];  M[2] = t[2];
        M[3] = t[1];  M[4] = t[3];  M[5] = t[4];
        M[6] = t[2];  M[7] = t[4];  M[8] = t[5];
    }
    __syncthreads();

    if (threadIdx.x < 9) {
        const int k = threadIdx.x;
        float acc = 0.f;
        #pragma unroll
        for (int p = 0; p < 9; ++p)
            acc = fmaf(M[p], cg[p * 9 + k], acc);   // cg[(i*3+j)*9 + k]
        out[k] = acc;
    }
}

extern "C" void kernel_launch(void* const* d_in, const int* in_sizes, int n_in,
                              void* d_out, int out_size, void* d_ws, size_t ws_size,
                              hipStream_t stream) {
    const float* frac = (const float*)d_in[0];   // [N, 3] flat
    const float* cg   = (const float*)d_in[1];   // [3, 3, 9] flat
    float*       out  = (float*)d_out;           // [9]
    float*       ws   = (float*)d_ws;            // 6*GRID floats = 24 KB

    const long nfloats  = in_sizes[0];           // 3*N
    const long nrows    = nfloats / 3;
    const long nchunks  = nfloats / 3072;        // 12 KB chunks (exact: 8192)
    const long tail_row = nchunks * 1024;        // rows covered by pass 1

    tp_partial<<<GRID, BLK, 0, stream>>>(frac, ws, nchunks);
    tp_final<<<1, BLK, 0, stream>>>(frac, ws, cg, out, tail_row, nrows);
}

// Round 7
// 23.536 us; speedup vs baseline: 1.0357x; 1.0357x over previous
//
#include <hip/hip_runtime.h>

// out[k] = sum_n sum_{i,j} frac[n,i]*frac[n,j]*cg[i,j,k]
//        = sum_{i,j} M[i][j] * cg[i,j,k],  M = sum_n x x^T (3x3 symmetric, 6 uniques)
//
// Pass 1 (this round's variable: DENSE loads, fill-kernel access pattern):
//   wave W owns f4[768W .. 768W+768): 12 wave-loads v[q]=f4[768W+64q+lane],
//   16B lane stride -> 16 cache lines per instruction (vs 48 in R5).
//   Phase algebra: element m=4*(64c+lane)+j (c=12W+q) has m%3=(q+j+lane)%3;
//   relative bucket d=(q+j)%3 is COMPILE-TIME, lane phase pl=lane%3 is
//   loop-invariant -> 9 static buckets, one 3-way remap at the end (R4-verified).
//   Next-element (j=3 products) via rotate-by-1 shuffle; lane63 of q takes
//   lane0 of rot(v[q+1]). q=11/lane63 boundary is always a row end (768 f4 ==
//   0 mod 3 rows) -> cross products land in DISCARDED buckets, garbage safe.
//   Zero extra memory instructions vs R5.
// Pass 2: 1 block, coalesced float4 reads of transposed partials + tail + cg.
//
// R3 post-mortem: no per-block agent-scope atomics (L2 writeback x GRID = 131us).
// R6 post-mortem: GRID=1024 regressed; 2048 is best.

constexpr int BLK  = 256;
constexpr int GRID = 2048;
constexpr int WPB  = BLK / 64;              // 4 waves per block
constexpr long NWAVES = (long)GRID * WPB;   // 8192
// wave region = 768 float4 = 3072 floats = 1024 rows = 12 KB

__global__ __launch_bounds__(BLK) void tp_partial(const float* __restrict__ frac,
                                                  float* __restrict__ ws,
                                                  long nregions) {
    const int  lane = threadIdx.x & 63;
    const int  w    = threadIdx.x >> 6;
    const long wglb = (long)blockIdx.x * WPB + w;
    const float4* __restrict__ f4 = reinterpret_cast<const float4*>(frac);

    const int  src  = (lane + 1) & 63;      // rotate-up-by-1 source lane
    const bool is63 = (lane == 63);

    float r[3] = {0.f, 0.f, 0.f};           // squares, bucket d
    float p[3] = {0.f, 0.f, 0.f};           // pairs   m*(m+1)
    float k[3] = {0.f, 0.f, 0.f};           // skips   m*(m+2)

    for (long reg = wglb; reg < nregions; reg += NWAVES) {  // trip count 1 @ N=2^23
        const long base = reg * 768 + lane;
        float4 v[12];
        #pragma unroll
        for (int q = 0; q < 12; ++q)
            v[q] = f4[base + 64 * q];        // 12 dense loads in flight

        float rx[12], ry[12];
        #pragma unroll
        for (int q = 0; q < 12; ++q) {
            rx[q] = __shfl(v[q].x, src);     // lane l gets lane l+1's .x
            ry[q] = __shfl(v[q].y, src);
        }

        #pragma unroll
        for (int q = 0; q < 12; ++q) {
            // next-element pair for j=3: lane<63 -> rot of own chunk;
            // lane63 -> lane0 of NEXT chunk = rot(v[q+1]) evaluated at lane63.
            // q=11/lane63: garbage, provably lands in discarded buckets.
            const float ex = (q < 11) ? (is63 ? rx[q + 1] : rx[q]) : rx[q];
            const float ey = (q < 11) ? (is63 ? ry[q + 1] : ry[q]) : ry[q];
            constexpr int D0[12] = {0,1,2,0,1,2,0,1,2,0,1,2};
            const int d0 = D0[q], d1 = D0[(q + 1) % 12], d2 = D0[(q + 2) % 12];
            const float h0 = v[q].x, h1 = v[q].y, h2 = v[q].z, h3 = v[q].w;
            r[d0] = fmaf(h0, h0, r[d0]);
            r[d1] = fmaf(h1, h1, r[d1]);
            r[d2] = fmaf(h2, h2, r[d2]);
            r[d0] = fmaf(h3, h3, r[d0]);
            p[d0] = fmaf(h0, h1, p[d0]);
            p[d1] = fmaf(h1, h2, p[d1]);
            p[d2] = fmaf(h2, h3, p[d2]);
            p[d0] = fmaf(h3, ex, p[d0]);
            k[d0] = fmaf(h0, h2, k[d0]);
            k[d1] = fmaf(h1, h3, k[d1]);
            k[d2] = fmaf(h2, ex, k[d2]);
            k[d0] = fmaf(h3, ey, k[d0]);
        }
    }

    // per-lane remap: abs phase = (d + pl) % 3 (R4-verified 3-way map)
    float s00, s01, s02, s11, s12, s22;
    const int pl = lane % 3;
    if (pl == 0)      { s00=r[0]; s11=r[1]; s22=r[2]; s01=p[0]; s12=p[1]; s02=k[0]; }
    else if (pl == 1) { s00=r[2]; s11=r[0]; s22=r[1]; s01=p[2]; s12=p[0]; s02=k[2]; }
    else              { s00=r[1]; s11=r[2]; s22=r[0]; s01=p[1]; s12=p[2]; s02=k[1]; }

    // 64-lane butterfly reduction
    #pragma unroll
    for (int off = 32; off > 0; off >>= 1) {
        s00 += __shfl_down(s00, off);
        s01 += __shfl_down(s01, off);
        s02 += __shfl_down(s02, off);
        s11 += __shfl_down(s11, off);
        s12 += __shfl_down(s12, off);
        s22 += __shfl_down(s22, off);
    }

    __shared__ float red[WPB][6];
    if (lane == 0) {
        red[w][0] = s00; red[w][1] = s01; red[w][2] = s02;
        red[w][3] = s11; red[w][4] = s12; red[w][5] = s22;
    }
    __syncthreads();
    if (threadIdx.x < 6) {
        float v = red[0][threadIdx.x] + red[1][threadIdx.x]
                + red[2][threadIdx.x] + red[3][threadIdx.x];
        ws[threadIdx.x * GRID + blockIdx.x] = v;   // transposed [6][GRID]
    }
}

__global__ __launch_bounds__(BLK) void tp_final(const float* __restrict__ frac,
                                                const float* __restrict__ ws,
                                                const float* __restrict__ cg,
                                                float* __restrict__ out,
                                                long tail_row, long nrows) {
    const float4* __restrict__ w4 = reinterpret_cast<const float4*>(ws); // [6][GRID/4]
    constexpr int Q = GRID / 4;   // 512 float4 per component

    float s[6];
    #pragma unroll
    for (int c = 0; c < 6; ++c) {
        float4 a = w4[c * Q + threadIdx.x];
        float4 b = w4[c * Q + threadIdx.x + BLK];
        s[c] = ((a.x + a.y) + (a.z + a.w)) + ((b.x + b.y) + (b.z + b.w));
    }

    // generic row tail (none for N = 2^23)
    for (long r = tail_row + threadIdx.x; r < nrows; r += BLK) {
        float x = frac[3 * r + 0], y = frac[3 * r + 1], z = frac[3 * r + 2];
        s[0] = fmaf(x, x, s[0]); s[1] = fmaf(x, y, s[1]); s[2] = fmaf(x, z, s[2]);
        s[3] = fmaf(y, y, s[3]); s[4] = fmaf(y, z, s[4]); s[5] = fmaf(z, z, s[5]);
    }

    #pragma unroll
    for (int off = 32; off > 0; off >>= 1) {
        #pragma unroll
        for (int c = 0; c < 6; ++c) s[c] += __shfl_down(s[c], off);
    }

    __shared__ float red[BLK / 64][6];
    const int lane = threadIdx.x & 63;
    const int wave = threadIdx.x >> 6;
    if (lane == 0) {
        #pragma unroll
        for (int c = 0; c < 6; ++c) red[wave][c] = s[c];
    }
    __syncthreads();

    __shared__ float M[9];
    if (threadIdx.x == 0) {
        float t[6];
        #pragma unroll
        for (int c = 0; c < 6; ++c)
            t[c] = red[0][c] + red[1][c] + red[2][c] + red[3][c];
        M[0] = t[0];  M[1] = t[1];  M[2] = t[2];
        M[3] = t[1];  M[4] = t[3];  M[5] = t[4];
        M[6] = t[2];  M[7] = t[4];  M[8] = t[5];
    }
    __syncthreads();

    if (threadIdx.x < 9) {
        const int kk = threadIdx.x;
        float acc = 0.f;
        #pragma unroll
        for (int pth = 0; pth < 9; ++pth)
            acc = fmaf(M[pth], cg[pth * 9 + kk], acc);   // cg[(i*3+j)*9 + k]
        out[kk] = acc;
    }
}

extern "C" void kernel_launch(void* const* d_in, const int* in_sizes, int n_in,
                              void* d_out, int out_size, void* d_ws, size_t ws_size,
                              hipStream_t stream) {
    const float* frac = (const float*)d_in[0];   // [N, 3] flat
    const float* cg   = (const float*)d_in[1];   // [3, 3, 9] flat
    float*       out  = (float*)d_out;           // [9]
    float*       ws   = (float*)d_ws;            // 6*GRID floats = 48 KB

    const long nfloats   = in_sizes[0];          // 3*N
    const long nrows     = nfloats / 3;
    const long nregions  = nfloats / 3072;       // 12 KB wave regions (exact: 8192)
    const long tail_row  = nregions * 1024;      // rows covered by pass 1

    tp_partial<<<GRID, BLK, 0, stream>>>(frac, ws, nregions);
    tp_final<<<1, BLK, 0, stream>>>(frac, ws, cg, out, tail_row, nrows);
}